// Round 7
// baseline (2293.873 us; speedup 1.0000x reference)
//
#include <hip/hip_runtime.h>
#include <math.h>

constexpr int B = 8;
constexpr int N = 50000;
constexpr int E = 400000;
constexpr float BN_EPS = 1e-5f;
constexpr float NEG = 0.01f;

// ------------------------- bf16 helpers -------------------------

__device__ __forceinline__ unsigned clamp_src(int s) {
    unsigned u = (unsigned)s;
    return (u < (unsigned)N) ? u : 0u;
}

__device__ __forceinline__ unsigned pack_bf16(float a, float b) {
    unsigned ua = __float_as_uint(a);
    unsigned ub = __float_as_uint(b);
    ua = (ua + 0x7FFFu + ((ua >> 16) & 1u)) >> 16;
    ub = (ub + 0x7FFFu + ((ub >> 16) & 1u)) >> 16;
    return (ub << 16) | (ua & 0xFFFFu);
}
__device__ __forceinline__ float unpack_lo(unsigned u) { return __uint_as_float(u << 16); }
__device__ __forceinline__ float unpack_hi(unsigned u) { return __uint_as_float(u & 0xFFFF0000u); }

// ------------------------- CSR construction -------------------------

__global__ __launch_bounds__(256) void deg_kernel(const int* __restrict__ col, float* __restrict__ deg) {
    int e = blockIdx.x * blockDim.x + threadIdx.x;
    if (e < E) atomicAdd(&deg[clamp_src(col[e])], 1.0f);
}

__global__ __launch_bounds__(256) void scan1_kernel(const float* __restrict__ deg,
                                                    int* __restrict__ part, int* __restrict__ bsum) {
    __shared__ int sm[4];
    int i = blockIdx.x * blockDim.x + threadIdx.x;
    int v = (i < N) ? (int)deg[i] : 0;
    int lane = threadIdx.x & 63, wv = threadIdx.x >> 6;
    int x = v;
#pragma unroll
    for (int off = 1; off < 64; off <<= 1) {
        int t = __shfl_up(x, off);
        if (lane >= off) x += t;
    }
    if (lane == 63) sm[wv] = x;
    __syncthreads();
    int add = 0;
#pragma unroll
    for (int w = 0; w < 4; ++w) if (w < wv) add += sm[w];
    if (i < N) part[i] = x - v + add;
    if (threadIdx.x == blockDim.x - 1) bsum[blockIdx.x] = x + add;
}

__global__ __launch_bounds__(256) void scan2_kernel(const int* __restrict__ bsum, int* __restrict__ boff,
                                                    int nb, int* __restrict__ rowptr) {
    __shared__ int sm[4];
    int i = threadIdx.x;
    int v = (i < nb) ? bsum[i] : 0;
    int lane = i & 63, wv = i >> 6;
    int x = v;
#pragma unroll
    for (int off = 1; off < 64; off <<= 1) {
        int t = __shfl_up(x, off);
        if (lane >= off) x += t;
    }
    if (lane == 63) sm[wv] = x;
    __syncthreads();
    int add = 0;
#pragma unroll
    for (int w = 0; w < 4; ++w) if (w < wv) add += sm[w];
    if (i < nb) boff[i] = x - v + add;
    if (i == 0) rowptr[N] = E;
}

__global__ __launch_bounds__(256) void scan3_kernel(const int* __restrict__ part, const int* __restrict__ boff,
                                                    int* __restrict__ rowptr) {
    int i = blockIdx.x * blockDim.x + threadIdx.x;
    if (i < N) rowptr[i] = part[i] + boff[blockIdx.x];
}

__global__ __launch_bounds__(256) void fill_kernel(const int* __restrict__ row, const int* __restrict__ col,
                                                   const float* __restrict__ deg, const int* __restrict__ rowptr,
                                                   int* __restrict__ cursor, int* __restrict__ csr_src,
                                                   float* __restrict__ csr_w) {
    int e = blockIdx.x * blockDim.x + threadIdx.x;
    if (e >= E) return;
    unsigned r = clamp_src(row[e]), c = clamp_src(col[e]);
    float dr = deg[r], dc = deg[c];
    float w = (dr > 0.f ? rsqrtf(dr) : 0.f) * (dc > 0.f ? rsqrtf(dc) : 0.f);
    unsigned p = (unsigned)(rowptr[c] + atomicAdd(&cursor[c], 1));
    if (p >= (unsigned)E) p = E - 1;
    csr_src[p] = (int)r;
    csr_w[p] = w;
}

// ------------------------- 4-dim propagation (layer 0), batch-pinned, bf16 out ---------

template<bool INBF>
__global__ __launch_bounds__(256) void xprop_kernel(const void* __restrict__ xin, const int* __restrict__ rowptr,
                                                    const int* __restrict__ csr_src, const float* __restrict__ csr_w,
                                                    uint2* __restrict__ xout) {
    int b = blockIdx.x & 7;
    int n = (blockIdx.x >> 3) * blockDim.x + threadIdx.x;
    if (n >= N) return;
    float a0 = 0.f, a1 = 0.f, a2 = 0.f, a3 = 0.f;
    int beg = rowptr[n], end = rowptr[n + 1];
    if (beg < 0) beg = 0;
    if (end > E) end = E;
    for (int i = beg; i < end; ++i) {
        unsigned s = clamp_src(csr_src[i]);
        float w = csr_w[i];
        if constexpr (!INBF) {
            float4 v = *((const float4*)xin + (size_t)b * N + s);
            a0 = fmaf(w, v.x, a0); a1 = fmaf(w, v.y, a1);
            a2 = fmaf(w, v.z, a2); a3 = fmaf(w, v.w, a3);
        } else {
            uint2 v = *((const uint2*)xin + (size_t)b * N + s);
            a0 = fmaf(w, unpack_lo(v.x), a0); a1 = fmaf(w, unpack_hi(v.x), a1);
            a2 = fmaf(w, unpack_lo(v.y), a2); a3 = fmaf(w, unpack_hi(v.y), a3);
        }
    }
    uint2 o;
    o.x = pack_bf16(a0, a1);
    o.y = pack_bf16(a2, a3);
    xout[(size_t)b * N + n] = o;
}

// ------------------------- 16-dim concat row loader -------------------------

__device__ __forceinline__ void load_xv(const float4* __restrict__ x0, const uint2* __restrict__ x1,
                                        const uint2* __restrict__ x2, const uint2* __restrict__ x3,
                                        size_t ro, float xv[16]) {
    float4 v = x0[ro];
    xv[0] = v.x; xv[1] = v.y; xv[2] = v.z; xv[3] = v.w;
    uint2 u1 = x1[ro], u2 = x2[ro], u3 = x3[ro];
    xv[4] = unpack_lo(u1.x); xv[5] = unpack_hi(u1.x); xv[6] = unpack_lo(u1.y); xv[7] = unpack_hi(u1.y);
    xv[8] = unpack_lo(u2.x); xv[9] = unpack_hi(u2.x); xv[10] = unpack_lo(u2.y); xv[11] = unpack_hi(u2.y);
    xv[12] = unpack_lo(u3.x); xv[13] = unpack_hi(u3.x); xv[14] = unpack_lo(u3.y); xv[15] = unpack_hi(u3.y);
}

// ------------------------- build h1 = leaky(BN0([x|x1|x2|x3] @ W0)), bf16 full batch ----
// Wave per node; lane = fg*8 + b; BN over batch via shfl_xor(1,2,4).

__global__ __launch_bounds__(256) void build_h1_kernel(const float4* __restrict__ x0, const uint2* __restrict__ x1,
                                                       const uint2* __restrict__ x2, const uint2* __restrict__ x3,
                                                       const float* __restrict__ W0,
                                                       const float* __restrict__ gamma, const float* __restrict__ beta,
                                                       uint4* __restrict__ h1) {
    int gid = blockIdx.x * blockDim.x + threadIdx.x;
    int node = gid >> 6;
    int lane = gid & 63;
    int fg = lane >> 3, b = lane & 7;
    if (node >= N) return;
    size_t ro = (size_t)b * N + node;
    float xv[16];
    load_xv(x0, x1, x2, x3, ro, xv);
    float z[8];
#pragma unroll
    for (int j = 0; j < 8; ++j) z[j] = 0.f;
#pragma unroll
    for (int kf = 0; kf < 16; ++kf) {
        const float* wr = W0 + kf * 64 + fg * 8;
        float4 wa = *(const float4*)wr;
        float4 wb = *(const float4*)(wr + 4);
        float xs = xv[kf];
        z[0] = fmaf(xs, wa.x, z[0]); z[1] = fmaf(xs, wa.y, z[1]);
        z[2] = fmaf(xs, wa.z, z[2]); z[3] = fmaf(xs, wa.w, z[3]);
        z[4] = fmaf(xs, wb.x, z[4]); z[5] = fmaf(xs, wb.y, z[5]);
        z[6] = fmaf(xs, wb.z, z[6]); z[7] = fmaf(xs, wb.w, z[7]);
    }
    const float* gp = gamma + (size_t)node * 64 + fg * 8;
    const float* bp = beta + (size_t)node * 64 + fg * 8;
    float h[8];
#pragma unroll
    for (int j = 0; j < 8; ++j) {
        float v = z[j];
        float s = v, s2 = v * v;
        s += __shfl_xor(s, 1);  s += __shfl_xor(s, 2);  s += __shfl_xor(s, 4);
        s2 += __shfl_xor(s2, 1); s2 += __shfl_xor(s2, 2); s2 += __shfl_xor(s2, 4);
        float mean = s * 0.125f;
        float var = fmaf(-mean, mean, s2 * 0.125f);
        float rs = rsqrtf(var + BN_EPS);
        float o = fmaf(gp[j] * rs, v - mean, bp[j]);
        h[j] = (o >= 0.f) ? o : NEG * o;
    }
    uint4 o;
    o.x = pack_bf16(h[0], h[1]);
    o.y = pack_bf16(h[2], h[3]);
    o.z = pack_bf16(h[4], h[5]);
    o.w = pack_bf16(h[6], h[7]);
    h1[ro * 8 + fg] = o;
}

// ------------------------- half-row gather + dense (32 features / thread) ---------------

__device__ __forceinline__ void gather32_bf(const uint4* __restrict__ ubase, int beg, int end,
                                            const int* __restrict__ csr_src, const float* __restrict__ csr_w,
                                            float acc[32]) {
    if (beg < 0) beg = 0;
    if (end > E) end = E;
    for (int i = beg; i < end; ++i) {
        unsigned s = clamp_src(csr_src[i]);
        float w = csr_w[i];
        const uint4* up = ubase + (size_t)s * 8;   // ubase pre-offset by half*4
#pragma unroll
        for (int q = 0; q < 4; ++q) {
            uint4 v = up[q];
            acc[q * 8 + 0] = fmaf(w, unpack_lo(v.x), acc[q * 8 + 0]);
            acc[q * 8 + 1] = fmaf(w, unpack_hi(v.x), acc[q * 8 + 1]);
            acc[q * 8 + 2] = fmaf(w, unpack_lo(v.y), acc[q * 8 + 2]);
            acc[q * 8 + 3] = fmaf(w, unpack_hi(v.y), acc[q * 8 + 3]);
            acc[q * 8 + 4] = fmaf(w, unpack_lo(v.z), acc[q * 8 + 4]);
            acc[q * 8 + 5] = fmaf(w, unpack_hi(v.z), acc[q * 8 + 5]);
            acc[q * 8 + 6] = fmaf(w, unpack_lo(v.w), acc[q * 8 + 6]);
            acc[q * 8 + 7] = fmaf(w, unpack_hi(v.w), acc[q * 8 + 7]);
        }
    }
}

// W pre-offset by half*32; full 64-k h row read (both halves share the cache line)
__device__ __forceinline__ void dense32_bf(const uint4* __restrict__ hp8, const float* __restrict__ W, float acc[32]) {
#pragma unroll 1
    for (int kk = 0; kk < 8; ++kk) {
        uint4 va = hp8[kk];
        float hreg[8];
        hreg[0] = unpack_lo(va.x); hreg[1] = unpack_hi(va.x);
        hreg[2] = unpack_lo(va.y); hreg[3] = unpack_hi(va.y);
        hreg[4] = unpack_lo(va.z); hreg[5] = unpack_hi(va.z);
        hreg[6] = unpack_lo(va.w); hreg[7] = unpack_hi(va.w);
        const float* Wp = W + kk * 8 * 64;
#pragma unroll
        for (int k = 0; k < 8; ++k) {
            float hv = hreg[k];
#pragma unroll
            for (int c = 0; c < 32; ++c)
                acc[c] = fmaf(hv, Wp[k * 64 + c], acc[c]);
        }
    }
}

// ------------------------- Horner hop, split 2 threads/row -------------------------
// MODE 0: u_out = h1@Wk. MODE 1: u_out = A u_in + h1@Wk. MODE 2: + bias.
// Thread = (batch bl, node n, half). bl = blockIdx & bmask -> batch->XCD pinning.

template<int MODE>
__global__ __launch_bounds__(256, 8) void hopS_kernel(const uint4* __restrict__ u_in, const int* __restrict__ rowptr,
                                                      const int* __restrict__ csr_src, const float* __restrict__ csr_w,
                                                      const uint4* __restrict__ h1, int b0, int bmask, int bshift,
                                                      const float* __restrict__ Wk, const float* __restrict__ bias,
                                                      uint4* __restrict__ u_out) {
    int bl = blockIdx.x & bmask;
    int lin = (blockIdx.x >> bshift) * blockDim.x + threadIdx.x;
    int half = lin & 1;
    int n = lin >> 1;
    if (n >= N) return;
    float acc[32];
    if constexpr (MODE == 2) {
        const float* bp = bias + half * 32;
#pragma unroll
        for (int f = 0; f < 32; ++f) acc[f] = bp[f];
    } else {
#pragma unroll
        for (int f = 0; f < 32; ++f) acc[f] = 0.f;
    }
    if constexpr (MODE > 0)
        gather32_bf(u_in + (size_t)bl * N * 8 + half * 4, rowptr[n], rowptr[n + 1], csr_src, csr_w, acc);
    dense32_bf(h1 + ((size_t)(b0 + bl) * N + n) * 8, Wk + half * 32, acc);
    uint4* op = u_out + ((size_t)bl * N + n) * 8 + half * 4;
#pragma unroll
    for (int q = 0; q < 4; ++q) {
        uint4 v;
        v.x = pack_bf16(acc[q * 8 + 0], acc[q * 8 + 1]);
        v.y = pack_bf16(acc[q * 8 + 2], acc[q * 8 + 3]);
        v.z = pack_bf16(acc[q * 8 + 4], acc[q * 8 + 5]);
        v.w = pack_bf16(acc[q * 8 + 6], acc[q * 8 + 7]);
        op[q] = v;
    }
}

// ------------------------- BN1 + leaky + W2 projection -------------------------
// Wave per node; lane = fg*8 + b. BN over b via xor(1,2,4); projection partials
// reduced over fg via xor(8,16,32).

__global__ __launch_bounds__(256) void bn_project_kernel(const uint4* __restrict__ zlo, const uint4* __restrict__ zhi,
                                                         const float* __restrict__ gamma, const float* __restrict__ beta,
                                                         const float* __restrict__ W2, float* __restrict__ y) {
    int gid = blockIdx.x * blockDim.x + threadIdx.x;
    int node = gid >> 6;
    int lane = gid & 63;
    int fg = lane >> 3, b = lane & 7;
    if (node >= N) return;
    const uint4* zp = (b < 4) ? (zlo + ((size_t)b * N + node) * 8)
                              : (zhi + ((size_t)(b - 4) * N + node) * 8);
    uint4 v = zp[fg];
    float h[8] = {unpack_lo(v.x), unpack_hi(v.x), unpack_lo(v.y), unpack_hi(v.y),
                  unpack_lo(v.z), unpack_hi(v.z), unpack_lo(v.w), unpack_hi(v.w)};
    const float* gp = gamma + (size_t)node * 64 + fg * 8;
    const float* bp = beta + (size_t)node * 64 + fg * 8;
#pragma unroll
    for (int j = 0; j < 8; ++j) {
        float val = h[j];
        float s = val, s2 = val * val;
        s += __shfl_xor(s, 1);  s += __shfl_xor(s, 2);  s += __shfl_xor(s, 4);
        s2 += __shfl_xor(s2, 1); s2 += __shfl_xor(s2, 2); s2 += __shfl_xor(s2, 4);
        float mean = s * 0.125f;
        float var = fmaf(-mean, mean, s2 * 0.125f);
        float rs = rsqrtf(var + BN_EPS);
        float o = fmaf(gp[j] * rs, val - mean, bp[j]);
        h[j] = (o >= 0.f) ? o : NEG * o;
    }
    float p[12];
#pragma unroll
    for (int k = 0; k < 4; ++k) {
#pragma unroll
        for (int c = 0; c < 3; ++c) {
            float s = 0.f;
#pragma unroll
            for (int j = 0; j < 8; ++j)
                s = fmaf(h[j], W2[k * 192 + (fg * 8 + j) * 3 + c], s);
            p[k * 3 + c] = s;
        }
    }
#pragma unroll
    for (int t = 8; t < 64; t <<= 1) {
#pragma unroll
        for (int i = 0; i < 12; ++i)
            p[i] += __shfl_xor(p[i], t);
    }
    if (fg == 0) {
        size_t bn3 = ((size_t)b * N + node) * 3;
#pragma unroll
        for (int k = 0; k < 4; ++k)
#pragma unroll
            for (int c = 0; c < 3; ++c)
                y[(size_t)k * B * N * 3 + bn3 + c] = p[k * 3 + c];
    }
}

// ------------------------- 3-dim propagation (layer 2 Horner) -------------------------

__global__ __launch_bounds__(256) void qprop_kernel(const float* __restrict__ vin, const int* __restrict__ rowptr,
                                                    const int* __restrict__ csr_src, const float* __restrict__ csr_w,
                                                    const float* __restrict__ add, float* __restrict__ vout) {
    int b = blockIdx.x & 7;
    int n = (blockIdx.x >> 3) * blockDim.x + threadIdx.x;
    if (n >= N) return;
    float a0 = 0.f, a1 = 0.f, a2 = 0.f;
    int beg = rowptr[n], end = rowptr[n + 1];
    if (beg < 0) beg = 0;
    if (end > E) end = E;
    const float* base = vin + (size_t)b * N * 3;
    for (int i = beg; i < end; ++i) {
        unsigned s = clamp_src(csr_src[i]);
        float w = csr_w[i];
        const float* p = base + (size_t)s * 3;
        a0 = fmaf(w, p[0], a0);
        a1 = fmaf(w, p[1], a1);
        a2 = fmaf(w, p[2], a2);
    }
    const float* ap = add + ((size_t)b * N + n) * 3;
    float* op = vout + ((size_t)b * N + n) * 3;
    op[0] = a0 + ap[0];
    op[1] = a1 + ap[1];
    op[2] = a2 + ap[2];
}

__global__ __launch_bounds__(256) void qfinal_kernel(const float* __restrict__ vin, const int* __restrict__ rowptr,
                                                     const int* __restrict__ csr_src, const float* __restrict__ csr_w,
                                                     const float* __restrict__ y0, const float* __restrict__ b2,
                                                     const float* __restrict__ vmin, const float* __restrict__ vmax,
                                                     float* __restrict__ out) {
    int b = blockIdx.x & 7;
    int n = (blockIdx.x >> 3) * blockDim.x + threadIdx.x;
    if (n >= N) return;
    float a0 = 0.f, a1 = 0.f, a2 = 0.f;
    int beg = rowptr[n], end = rowptr[n + 1];
    if (beg < 0) beg = 0;
    if (end > E) end = E;
    const float* base = vin + (size_t)b * N * 3;
    for (int i = beg; i < end; ++i) {
        unsigned s = clamp_src(csr_src[i]);
        float w = csr_w[i];
        const float* p = base + (size_t)s * 3;
        a0 = fmaf(w, p[0], a0);
        a1 = fmaf(w, p[1], a1);
        a2 = fmaf(w, p[2], a2);
    }
    size_t bn3 = ((size_t)b * N + n) * 3;
    const float* yp = y0 + bn3;
    float g0 = a0 + yp[0] + b2[0];
    float g1 = a1 + yp[1] + b2[1];
    float g2 = a2 + yp[2] + b2[2];
    float mn0 = vmin[n * 3 + 0], mx0 = vmax[n * 3 + 0];
    float mn1 = vmin[n * 3 + 1], mx1 = vmax[n * 3 + 1];
    float mn2 = vmin[n * 3 + 2], mx2 = vmax[n * 3 + 2];
    float* op = out + bn3;
    op[0] = mn0 + (mx0 - mn0) / (1.f + expf(g0));
    op[1] = mn1 + (mx1 - mn1) / (1.f + expf(g1));
    op[2] = mn2 + (mx2 - mn2) / (1.f + expf(g2));
}

// ------------------------- host launcher -------------------------

extern "C" void kernel_launch(void* const* d_in, const int* in_sizes, int n_in,
                              void* d_out, int out_size, void* d_ws, size_t ws_size,
                              hipStream_t stream) {
    const float* x      = (const float*)d_in[0];
    const int*   ei     = (const int*)d_in[1];
    const int*   rowi   = ei;
    const int*   coli   = ei + E;
    const float* vmin   = (const float*)d_in[2];
    const float* vmax   = (const float*)d_in[3];
    const float* W0     = (const float*)d_in[4];
    const float* W1     = (const float*)d_in[6];
    const float* b1v    = (const float*)d_in[7];
    const float* W2     = (const float*)d_in[8];
    const float* b2v    = (const float*)d_in[9];
    const float* gamma0 = (const float*)d_in[10];
    const float* beta0  = (const float*)d_in[11];
    const float* gamma1 = (const float*)d_in[12];
    const float* beta1  = (const float*)d_in[13];
    float* out = (float*)d_out;

    const size_t BN3  = (size_t)B * N * 3;
    const size_t H1FL = (size_t)B * N * 32;        // 12.8M fl = 51.2 MB
    const size_t UCFL = (size_t)4 * N * 32;        // 6.4M fl  = 25.6 MB
    const size_t XBFL = (size_t)B * N * 2;

    auto rnd = [](size_t nf) { return (nf + 63) & ~(size_t)63; };
    size_t off = 0;
    auto alloc = [&](size_t nfloats) -> float* {
        float* p = (float*)d_ws + off;
        off += rnd(nfloats);
        return p;
    };
    float* deg     = alloc(N);
    float* csr_w   = alloc(E);
    int*   rowptr  = (int*)alloc(N + 1);
    int*   part    = (int*)alloc(N);
    int*   bsum    = (int*)alloc(256);
    int*   boff    = (int*)alloc(256);
    int*   cursor  = (int*)alloc(N);
    int*   csr_src = (int*)alloc(E);
    float* h1      = alloc(H1FL);

    const size_t avail_fl = ws_size / 4;
    const size_t need_full = off + 2 * H1FL + 4096;
    bool full = (avail_fl >= need_full);

    float *uA, *uB, *uC = nullptr;
    if (full) {
        uA = alloc(H1FL);
        uB = alloc(H1FL);
    } else {
        uA = alloc(UCFL);
        uB = alloc(UCFL);
        uC = alloc(UCFL);
    }
    uint2* xb1 = (uint2*)uA;
    uint2* xb2 = (uint2*)((float*)uA + XBFL);
    uint2* xb3 = (uint2*)((float*)uA + 2 * XBFL);
    float* y   = h1;
    float* v_a = h1 + rnd(4 * BN3);
    float* v_b = v_a + rnd(BN3);

    const int GE  = (E + 255) / 256;
    const int GN  = (N + 255) / 256;               // 196
    const int GB8 = GN * 8;
    const int GNH = (2 * N + 255) / 256;           // 391 blocks per batch (split rows)
    const int GW  = (N * 64) / 256;                // 12500 wave-per-node blocks
    dim3 blk(256);

    // CSR build
    hipMemsetAsync(deg, 0, N * sizeof(float), stream);
    hipMemsetAsync(cursor, 0, N * sizeof(int), stream);
    deg_kernel<<<GE, blk, 0, stream>>>(coli, deg);
    scan1_kernel<<<GN, blk, 0, stream>>>(deg, part, bsum);
    scan2_kernel<<<1, blk, 0, stream>>>(bsum, boff, GN, rowptr);
    scan3_kernel<<<GN, blk, 0, stream>>>(part, boff, rowptr);
    fill_kernel<<<GE, blk, 0, stream>>>(rowi, coli, deg, rowptr, cursor, csr_src, csr_w);

    // layer 0
    xprop_kernel<false><<<GB8, blk, 0, stream>>>(x,   rowptr, csr_src, csr_w, xb1);
    xprop_kernel<true><<<GB8, blk, 0, stream>>>(xb1, rowptr, csr_src, csr_w, xb2);
    xprop_kernel<true><<<GB8, blk, 0, stream>>>(xb2, rowptr, csr_src, csr_w, xb3);
    build_h1_kernel<<<GW, blk, 0, stream>>>((const float4*)x, xb1, xb2, xb3, W0, gamma0, beta0, (uint4*)h1);

    const uint4* H1 = (const uint4*)h1;
    if (full) {
        hopS_kernel<0><<<GNH * 8, blk, 0, stream>>>(nullptr, rowptr, csr_src, csr_w, H1, 0, 7, 3,
                                                    W1 + 3 * 4096, nullptr, (uint4*)uA);
        hopS_kernel<1><<<GNH * 8, blk, 0, stream>>>((const uint4*)uA, rowptr, csr_src, csr_w, H1, 0, 7, 3,
                                                    W1 + 2 * 4096, nullptr, (uint4*)uB);
        hopS_kernel<1><<<GNH * 8, blk, 0, stream>>>((const uint4*)uB, rowptr, csr_src, csr_w, H1, 0, 7, 3,
                                                    W1 + 1 * 4096, nullptr, (uint4*)uA);
        hopS_kernel<2><<<GNH * 8, blk, 0, stream>>>((const uint4*)uA, rowptr, csr_src, csr_w, H1, 0, 7, 3,
                                                    W1, b1v, (uint4*)uB);
        bn_project_kernel<<<GW, blk, 0, stream>>>((const uint4*)uB, (const uint4*)(uB + 4 * (size_t)N * 32),
                                                  gamma1, beta1, W2, y);
    } else {
        hopS_kernel<0><<<GNH * 8, blk, 0, stream>>>(nullptr, rowptr, csr_src, csr_w, H1, 0, 7, 3,
                                                    W1 + 3 * 4096, nullptr, (uint4*)uA);
        // lo chunk: uA -> uC -> uA -> uC(z_lo)
        hopS_kernel<1><<<GNH * 4, blk, 0, stream>>>((const uint4*)uA, rowptr, csr_src, csr_w, H1, 0, 3, 2,
                                                    W1 + 2 * 4096, nullptr, (uint4*)uC);
        hopS_kernel<1><<<GNH * 4, blk, 0, stream>>>((const uint4*)uC, rowptr, csr_src, csr_w, H1, 0, 3, 2,
                                                    W1 + 1 * 4096, nullptr, (uint4*)uA);
        hopS_kernel<2><<<GNH * 4, blk, 0, stream>>>((const uint4*)uA, rowptr, csr_src, csr_w, H1, 0, 3, 2,
                                                    W1, b1v, (uint4*)uC);
        // hi chunk: uB -> uA -> uB -> uA(z_hi)
        hopS_kernel<1><<<GNH * 4, blk, 0, stream>>>((const uint4*)uB, rowptr, csr_src, csr_w, H1, 4, 3, 2,
                                                    W1 + 2 * 4096, nullptr, (uint4*)uA);
        hopS_kernel<1><<<GNH * 4, blk, 0, stream>>>((const uint4*)uA, rowptr, csr_src, csr_w, H1, 4, 3, 2,
                                                    W1 + 1 * 4096, nullptr, (uint4*)uB);
        hopS_kernel<2><<<GNH * 4, blk, 0, stream>>>((const uint4*)uB, rowptr, csr_src, csr_w, H1, 4, 3, 2,
                                                    W1, b1v, (uint4*)uA);
        bn_project_kernel<<<GW, blk, 0, stream>>>((const uint4*)uC, (const uint4*)uA,
                                                  gamma1, beta1, W2, y);
    }

    // layer 2 Horner at 3-dim
    qprop_kernel<<<GB8, blk, 0, stream>>>(y + 3 * BN3, rowptr, csr_src, csr_w, y + 2 * BN3, v_a);
    qprop_kernel<<<GB8, blk, 0, stream>>>(v_a, rowptr, csr_src, csr_w, y + 1 * BN3, v_b);
    qfinal_kernel<<<GB8, blk, 0, stream>>>(v_b, rowptr, csr_src, csr_w, y, b2v, vmin, vmax, out);
}

// Round 8
// 928.251 us; speedup vs baseline: 2.4712x; 2.4712x over previous
//
#include <hip/hip_runtime.h>
#include <math.h>

constexpr int B = 8;
constexpr int N = 50000;
constexpr int E = 400000;
constexpr float BN_EPS = 1e-5f;
constexpr float NEG = 0.01f;

// ------------------------- bf16 helpers -------------------------

__device__ __forceinline__ unsigned clamp_src(int s) {
    unsigned u = (unsigned)s;
    return (u < (unsigned)N) ? u : 0u;
}

__device__ __forceinline__ unsigned pack_bf16(float a, float b) {
    unsigned ua = __float_as_uint(a);
    unsigned ub = __float_as_uint(b);
    ua = (ua + 0x7FFFu + ((ua >> 16) & 1u)) >> 16;
    ub = (ub + 0x7FFFu + ((ub >> 16) & 1u)) >> 16;
    return (ub << 16) | (ua & 0xFFFFu);
}
__device__ __forceinline__ float unpack_lo(unsigned u) { return __uint_as_float(u << 16); }
__device__ __forceinline__ float unpack_hi(unsigned u) { return __uint_as_float(u & 0xFFFF0000u); }

__device__ __forceinline__ void store_row64_bf(uint4* p, const float acc[64]) {
#pragma unroll
    for (int q = 0; q < 8; ++q) {
        uint4 v;
        v.x = pack_bf16(acc[q * 8 + 0], acc[q * 8 + 1]);
        v.y = pack_bf16(acc[q * 8 + 2], acc[q * 8 + 3]);
        v.z = pack_bf16(acc[q * 8 + 4], acc[q * 8 + 5]);
        v.w = pack_bf16(acc[q * 8 + 6], acc[q * 8 + 7]);
        p[q] = v;
    }
}

// ------------------------- CSR construction -------------------------

__global__ __launch_bounds__(256) void deg_kernel(const int* __restrict__ col, float* __restrict__ deg) {
    int e = blockIdx.x * blockDim.x + threadIdx.x;
    if (e < E) atomicAdd(&deg[clamp_src(col[e])], 1.0f);
}

__global__ __launch_bounds__(256) void scan1_kernel(const float* __restrict__ deg,
                                                    int* __restrict__ part, int* __restrict__ bsum) {
    __shared__ int sm[4];
    int i = blockIdx.x * blockDim.x + threadIdx.x;
    int v = (i < N) ? (int)deg[i] : 0;
    int lane = threadIdx.x & 63, wv = threadIdx.x >> 6;
    int x = v;
#pragma unroll
    for (int off = 1; off < 64; off <<= 1) {
        int t = __shfl_up(x, off);
        if (lane >= off) x += t;
    }
    if (lane == 63) sm[wv] = x;
    __syncthreads();
    int add = 0;
#pragma unroll
    for (int w = 0; w < 4; ++w) if (w < wv) add += sm[w];
    if (i < N) part[i] = x - v + add;
    if (threadIdx.x == blockDim.x - 1) bsum[blockIdx.x] = x + add;
}

__global__ __launch_bounds__(256) void scan2_kernel(const int* __restrict__ bsum, int* __restrict__ boff,
                                                    int nb, int* __restrict__ rowptr) {
    __shared__ int sm[4];
    int i = threadIdx.x;
    int v = (i < nb) ? bsum[i] : 0;
    int lane = i & 63, wv = i >> 6;
    int x = v;
#pragma unroll
    for (int off = 1; off < 64; off <<= 1) {
        int t = __shfl_up(x, off);
        if (lane >= off) x += t;
    }
    if (lane == 63) sm[wv] = x;
    __syncthreads();
    int add = 0;
#pragma unroll
    for (int w = 0; w < 4; ++w) if (w < wv) add += sm[w];
    if (i < nb) boff[i] = x - v + add;
    if (i == 0) rowptr[N] = E;
}

__global__ __launch_bounds__(256) void scan3_kernel(const int* __restrict__ part, const int* __restrict__ boff,
                                                    int* __restrict__ rowptr) {
    int i = blockIdx.x * blockDim.x + threadIdx.x;
    if (i < N) rowptr[i] = part[i] + boff[blockIdx.x];
}

__global__ __launch_bounds__(256) void fill_kernel(const int* __restrict__ row, const int* __restrict__ col,
                                                   const int* __restrict__ rowptr,
                                                   int* __restrict__ cursor, int* __restrict__ csr_src) {
    int e = blockIdx.x * blockDim.x + threadIdx.x;
    if (e >= E) return;
    unsigned r = clamp_src(row[e]), c = clamp_src(col[e]);
    unsigned p = (unsigned)(rowptr[c] + atomicAdd(&cursor[c], 1));
    if (p >= (unsigned)E) p = E - 1;
    csr_src[p] = (int)r;
}

// deg -> dis (in place): dis = deg>0 ? deg^-1/2 : 0
__global__ __launch_bounds__(256) void dis_kernel(float* __restrict__ deg) {
    int i = blockIdx.x * blockDim.x + threadIdx.x;
    if (i < N) {
        float d = deg[i];
        deg[i] = (d > 0.f) ? rsqrtf(d) : 0.f;
    }
}

// ------------------------- 4-dim propagation (layer 0), batch-pinned, bf16 out ---------

template<bool INBF>
__global__ __launch_bounds__(256) void xprop_kernel(const void* __restrict__ xin, const int* __restrict__ rowptr,
                                                    const int* __restrict__ csr_src, const float* __restrict__ dis,
                                                    uint2* __restrict__ xout) {
    int b = blockIdx.x & 7;
    int n = (blockIdx.x >> 3) * blockDim.x + threadIdx.x;
    if (n >= N) return;
    float a0 = 0.f, a1 = 0.f, a2 = 0.f, a3 = 0.f;
    int beg = rowptr[n], end = rowptr[n + 1];
    if (beg < 0) beg = 0;
    if (end > E) end = E;
    for (int i = beg; i < end; ++i) {
        unsigned s = clamp_src(csr_src[i]);
        float w = dis[s];
        if constexpr (!INBF) {
            float4 v = *((const float4*)xin + (size_t)b * N + s);
            a0 = fmaf(w, v.x, a0); a1 = fmaf(w, v.y, a1);
            a2 = fmaf(w, v.z, a2); a3 = fmaf(w, v.w, a3);
        } else {
            uint2 v = *((const uint2*)xin + (size_t)b * N + s);
            a0 = fmaf(w, unpack_lo(v.x), a0); a1 = fmaf(w, unpack_hi(v.x), a1);
            a2 = fmaf(w, unpack_lo(v.y), a2); a3 = fmaf(w, unpack_hi(v.y), a3);
        }
    }
    float dn = dis[n];
    uint2 o;
    o.x = pack_bf16(a0 * dn, a1 * dn);
    o.y = pack_bf16(a2 * dn, a3 * dn);
    xout[(size_t)b * N + n] = o;
}

// ------------------------- 16-dim concat row loader -------------------------

__device__ __forceinline__ void load_xv(const float4* __restrict__ x0, const uint2* __restrict__ x1,
                                        const uint2* __restrict__ x2, const uint2* __restrict__ x3,
                                        size_t ro, float xv[16]) {
    float4 v = x0[ro];
    xv[0] = v.x; xv[1] = v.y; xv[2] = v.z; xv[3] = v.w;
    uint2 u1 = x1[ro], u2 = x2[ro], u3 = x3[ro];
    xv[4] = unpack_lo(u1.x); xv[5] = unpack_hi(u1.x); xv[6] = unpack_lo(u1.y); xv[7] = unpack_hi(u1.y);
    xv[8] = unpack_lo(u2.x); xv[9] = unpack_hi(u2.x); xv[10] = unpack_lo(u2.y); xv[11] = unpack_hi(u2.y);
    xv[12] = unpack_lo(u3.x); xv[13] = unpack_hi(u3.x); xv[14] = unpack_lo(u3.y); xv[15] = unpack_hi(u3.y);
}

// ------------------------- build h1 = leaky(BN0([x|x1|x2|x3] @ W0)), bf16 full batch ----

__global__ __launch_bounds__(256) void build_h1_kernel(const float4* __restrict__ x0, const uint2* __restrict__ x1,
                                                       const uint2* __restrict__ x2, const uint2* __restrict__ x3,
                                                       const float* __restrict__ W0,
                                                       const float* __restrict__ gamma, const float* __restrict__ beta,
                                                       uint4* __restrict__ h1) {
    int gid = blockIdx.x * blockDim.x + threadIdx.x;
    int node = gid >> 6;
    int lane = gid & 63;
    int fg = lane >> 3, b = lane & 7;
    if (node >= N) return;
    size_t ro = (size_t)b * N + node;
    float xv[16];
    load_xv(x0, x1, x2, x3, ro, xv);
    float z[8];
#pragma unroll
    for (int j = 0; j < 8; ++j) z[j] = 0.f;
#pragma unroll
    for (int kf = 0; kf < 16; ++kf) {
        const float* wr = W0 + kf * 64 + fg * 8;
        float4 wa = *(const float4*)wr;
        float4 wb = *(const float4*)(wr + 4);
        float xs = xv[kf];
        z[0] = fmaf(xs, wa.x, z[0]); z[1] = fmaf(xs, wa.y, z[1]);
        z[2] = fmaf(xs, wa.z, z[2]); z[3] = fmaf(xs, wa.w, z[3]);
        z[4] = fmaf(xs, wb.x, z[4]); z[5] = fmaf(xs, wb.y, z[5]);
        z[6] = fmaf(xs, wb.z, z[6]); z[7] = fmaf(xs, wb.w, z[7]);
    }
    const float* gp = gamma + (size_t)node * 64 + fg * 8;
    const float* bp = beta + (size_t)node * 64 + fg * 8;
    float h[8];
#pragma unroll
    for (int j = 0; j < 8; ++j) {
        float v = z[j];
        float s = v, s2 = v * v;
        s += __shfl_xor(s, 1);  s += __shfl_xor(s, 2);  s += __shfl_xor(s, 4);
        s2 += __shfl_xor(s2, 1); s2 += __shfl_xor(s2, 2); s2 += __shfl_xor(s2, 4);
        float mean = s * 0.125f;
        float var = fmaf(-mean, mean, s2 * 0.125f);
        float rs = rsqrtf(var + BN_EPS);
        float o = fmaf(gp[j] * rs, v - mean, bp[j]);
        h[j] = (o >= 0.f) ? o : NEG * o;
    }
    uint4 o;
    o.x = pack_bf16(h[0], h[1]);
    o.y = pack_bf16(h[2], h[3]);
    o.z = pack_bf16(h[4], h[5]);
    o.w = pack_bf16(h[6], h[7]);
    h1[ro * 8 + fg] = o;
}

// ------------------------- bf16 gather (pair-pipelined) + dense 64x64 -------------------

__device__ __forceinline__ void fma_row(float acc[64], float w, const uint4 r[8]) {
#pragma unroll
    for (int q = 0; q < 8; ++q) {
        uint4 v = r[q];
        acc[q * 8 + 0] = fmaf(w, unpack_lo(v.x), acc[q * 8 + 0]);
        acc[q * 8 + 1] = fmaf(w, unpack_hi(v.x), acc[q * 8 + 1]);
        acc[q * 8 + 2] = fmaf(w, unpack_lo(v.y), acc[q * 8 + 2]);
        acc[q * 8 + 3] = fmaf(w, unpack_hi(v.y), acc[q * 8 + 3]);
        acc[q * 8 + 4] = fmaf(w, unpack_lo(v.z), acc[q * 8 + 4]);
        acc[q * 8 + 5] = fmaf(w, unpack_hi(v.z), acc[q * 8 + 5]);
        acc[q * 8 + 6] = fmaf(w, unpack_lo(v.w), acc[q * 8 + 6]);
        acc[q * 8 + 7] = fmaf(w, unpack_hi(v.w), acc[q * 8 + 7]);
    }
}

__device__ __forceinline__ void gather64_bf(const uint4* __restrict__ ub8, int beg, int end,
                                            const int* __restrict__ csr_src, const float* __restrict__ dis,
                                            float acc[64]) {
    if (beg < 0) beg = 0;
    if (end > E) end = E;
    int i = beg;
    // two edges in flight per iteration: 16 outstanding dwordx4 loads
    for (; i + 1 < end; i += 2) {
        unsigned s0 = clamp_src(csr_src[i]);
        unsigned s1 = clamp_src(csr_src[i + 1]);
        float w0 = dis[s0], w1 = dis[s1];
        const uint4* p0 = ub8 + (size_t)s0 * 8;
        const uint4* p1 = ub8 + (size_t)s1 * 8;
        uint4 r0[8], r1[8];
#pragma unroll
        for (int q = 0; q < 8; ++q) r0[q] = p0[q];
#pragma unroll
        for (int q = 0; q < 8; ++q) r1[q] = p1[q];
        fma_row(acc, w0, r0);
        fma_row(acc, w1, r1);
    }
    if (i < end) {
        unsigned s0 = clamp_src(csr_src[i]);
        float w0 = dis[s0];
        const uint4* p0 = ub8 + (size_t)s0 * 8;
        uint4 r0[8];
#pragma unroll
        for (int q = 0; q < 8; ++q) r0[q] = p0[q];
        fma_row(acc, w0, r0);
    }
}

__device__ __forceinline__ void dense64_bf(const uint4* __restrict__ hp8, const float* __restrict__ W, float acc[64]) {
#pragma unroll 1
    for (int kk = 0; kk < 4; ++kk) {
        float hreg[16];
        uint4 va = hp8[kk * 2], vb = hp8[kk * 2 + 1];
        hreg[0] = unpack_lo(va.x); hreg[1] = unpack_hi(va.x);
        hreg[2] = unpack_lo(va.y); hreg[3] = unpack_hi(va.y);
        hreg[4] = unpack_lo(va.z); hreg[5] = unpack_hi(va.z);
        hreg[6] = unpack_lo(va.w); hreg[7] = unpack_hi(va.w);
        hreg[8] = unpack_lo(vb.x); hreg[9] = unpack_hi(vb.x);
        hreg[10] = unpack_lo(vb.y); hreg[11] = unpack_hi(vb.y);
        hreg[12] = unpack_lo(vb.z); hreg[13] = unpack_hi(vb.z);
        hreg[14] = unpack_lo(vb.w); hreg[15] = unpack_hi(vb.w);
        const float* Wp = W + kk * 16 * 64;
#pragma unroll
        for (int k = 0; k < 16; ++k) {
            float hv = hreg[k];
#pragma unroll
            for (int c = 0; c < 64; ++c)
                acc[c] = fmaf(hv, Wp[k * 64 + c], acc[c]);
        }
    }
}

// ------------------------- Horner hop (full 64-feature row / thread) -------------------
// MODE 0: u_out = h1@Wk. MODE 1: u_out = dis_n*(A' u_in) + h1@Wk. MODE 2: + bias.

template<int MODE>
__global__ __launch_bounds__(256) void hopM_kernel(const uint4* __restrict__ u_in, const int* __restrict__ rowptr,
                                                   const int* __restrict__ csr_src, const float* __restrict__ dis,
                                                   const uint4* __restrict__ h1, int b0, int bmask, int bshift,
                                                   const float* __restrict__ Wk, const float* __restrict__ bias,
                                                   uint4* __restrict__ u_out) {
    int bl = blockIdx.x & bmask;
    int n = (blockIdx.x >> bshift) * blockDim.x + threadIdx.x;
    if (n >= N) return;
    float acc[64];
#pragma unroll
    for (int f = 0; f < 64; ++f) acc[f] = 0.f;
    if constexpr (MODE > 0) {
        gather64_bf(u_in + (size_t)bl * N * 8, rowptr[n], rowptr[n + 1], csr_src, dis, acc);
        float dn = dis[n];
#pragma unroll
        for (int f = 0; f < 64; ++f) acc[f] *= dn;
    }
    if constexpr (MODE == 2) {
#pragma unroll
        for (int f = 0; f < 64; ++f) acc[f] += bias[f];
    }
    dense64_bf(h1 + ((size_t)(b0 + bl) * N + n) * 8, Wk, acc);
    store_row64_bf(u_out + ((size_t)bl * N + n) * 8, acc);
}

// ------------------------- BN1 + leaky + W2 projection -------------------------

__global__ __launch_bounds__(256) void bn_project_kernel(const uint4* __restrict__ zlo, const uint4* __restrict__ zhi,
                                                         const float* __restrict__ gamma, const float* __restrict__ beta,
                                                         const float* __restrict__ W2, float* __restrict__ y) {
    int gid = blockIdx.x * blockDim.x + threadIdx.x;
    int node = gid >> 6;
    int lane = gid & 63;
    int fg = lane >> 3, b = lane & 7;
    if (node >= N) return;
    const uint4* zp = (b < 4) ? (zlo + ((size_t)b * N + node) * 8)
                              : (zhi + ((size_t)(b - 4) * N + node) * 8);
    uint4 v = zp[fg];
    float h[8] = {unpack_lo(v.x), unpack_hi(v.x), unpack_lo(v.y), unpack_hi(v.y),
                  unpack_lo(v.z), unpack_hi(v.z), unpack_lo(v.w), unpack_hi(v.w)};
    const float* gp = gamma + (size_t)node * 64 + fg * 8;
    const float* bp = beta + (size_t)node * 64 + fg * 8;
#pragma unroll
    for (int j = 0; j < 8; ++j) {
        float val = h[j];
        float s = val, s2 = val * val;
        s += __shfl_xor(s, 1);  s += __shfl_xor(s, 2);  s += __shfl_xor(s, 4);
        s2 += __shfl_xor(s2, 1); s2 += __shfl_xor(s2, 2); s2 += __shfl_xor(s2, 4);
        float mean = s * 0.125f;
        float var = fmaf(-mean, mean, s2 * 0.125f);
        float rs = rsqrtf(var + BN_EPS);
        float o = fmaf(gp[j] * rs, val - mean, bp[j]);
        h[j] = (o >= 0.f) ? o : NEG * o;
    }
    float p[12];
#pragma unroll
    for (int k = 0; k < 4; ++k) {
#pragma unroll
        for (int c = 0; c < 3; ++c) {
            float s = 0.f;
#pragma unroll
            for (int j = 0; j < 8; ++j)
                s = fmaf(h[j], W2[k * 192 + (fg * 8 + j) * 3 + c], s);
            p[k * 3 + c] = s;
        }
    }
#pragma unroll
    for (int t = 8; t < 64; t <<= 1) {
#pragma unroll
        for (int i = 0; i < 12; ++i)
            p[i] += __shfl_xor(p[i], t);
    }
    if (fg == 0) {
        size_t bn3 = ((size_t)b * N + node) * 3;
#pragma unroll
        for (int k = 0; k < 4; ++k)
#pragma unroll
            for (int c = 0; c < 3; ++c)
                y[(size_t)k * B * N * 3 + bn3 + c] = p[k * 3 + c];
    }
}

// ------------------------- 3-dim propagation (layer 2 Horner) -------------------------

__global__ __launch_bounds__(256) void qprop_kernel(const float* __restrict__ vin, const int* __restrict__ rowptr,
                                                    const int* __restrict__ csr_src, const float* __restrict__ dis,
                                                    const float* __restrict__ add, float* __restrict__ vout) {
    int b = blockIdx.x & 7;
    int n = (blockIdx.x >> 3) * blockDim.x + threadIdx.x;
    if (n >= N) return;
    float a0 = 0.f, a1 = 0.f, a2 = 0.f;
    int beg = rowptr[n], end = rowptr[n + 1];
    if (beg < 0) beg = 0;
    if (end > E) end = E;
    const float* base = vin + (size_t)b * N * 3;
    for (int i = beg; i < end; ++i) {
        unsigned s = clamp_src(csr_src[i]);
        float w = dis[s];
        const float* p = base + (size_t)s * 3;
        a0 = fmaf(w, p[0], a0);
        a1 = fmaf(w, p[1], a1);
        a2 = fmaf(w, p[2], a2);
    }
    float dn = dis[n];
    const float* ap = add + ((size_t)b * N + n) * 3;
    float* op = vout + ((size_t)b * N + n) * 3;
    op[0] = fmaf(a0, dn, ap[0]);
    op[1] = fmaf(a1, dn, ap[1]);
    op[2] = fmaf(a2, dn, ap[2]);
}

__global__ __launch_bounds__(256) void qfinal_kernel(const float* __restrict__ vin, const int* __restrict__ rowptr,
                                                     const int* __restrict__ csr_src, const float* __restrict__ dis,
                                                     const float* __restrict__ y0, const float* __restrict__ b2,
                                                     const float* __restrict__ vmin, const float* __restrict__ vmax,
                                                     float* __restrict__ out) {
    int b = blockIdx.x & 7;
    int n = (blockIdx.x >> 3) * blockDim.x + threadIdx.x;
    if (n >= N) return;
    float a0 = 0.f, a1 = 0.f, a2 = 0.f;
    int beg = rowptr[n], end = rowptr[n + 1];
    if (beg < 0) beg = 0;
    if (end > E) end = E;
    const float* base = vin + (size_t)b * N * 3;
    for (int i = beg; i < end; ++i) {
        unsigned s = clamp_src(csr_src[i]);
        float w = dis[s];
        const float* p = base + (size_t)s * 3;
        a0 = fmaf(w, p[0], a0);
        a1 = fmaf(w, p[1], a1);
        a2 = fmaf(w, p[2], a2);
    }
    float dn = dis[n];
    size_t bn3 = ((size_t)b * N + n) * 3;
    const float* yp = y0 + bn3;
    float g0 = fmaf(a0, dn, yp[0]) + b2[0];
    float g1 = fmaf(a1, dn, yp[1]) + b2[1];
    float g2 = fmaf(a2, dn, yp[2]) + b2[2];
    float mn0 = vmin[n * 3 + 0], mx0 = vmax[n * 3 + 0];
    float mn1 = vmin[n * 3 + 1], mx1 = vmax[n * 3 + 1];
    float mn2 = vmin[n * 3 + 2], mx2 = vmax[n * 3 + 2];
    float* op = out + bn3;
    op[0] = mn0 + (mx0 - mn0) / (1.f + expf(g0));
    op[1] = mn1 + (mx1 - mn1) / (1.f + expf(g1));
    op[2] = mn2 + (mx2 - mn2) / (1.f + expf(g2));
}

// ------------------------- host launcher -------------------------

extern "C" void kernel_launch(void* const* d_in, const int* in_sizes, int n_in,
                              void* d_out, int out_size, void* d_ws, size_t ws_size,
                              hipStream_t stream) {
    const float* x      = (const float*)d_in[0];
    const int*   ei     = (const int*)d_in[1];
    const int*   rowi   = ei;
    const int*   coli   = ei + E;
    const float* vmin   = (const float*)d_in[2];
    const float* vmax   = (const float*)d_in[3];
    const float* W0     = (const float*)d_in[4];
    const float* W1     = (const float*)d_in[6];
    const float* b1v    = (const float*)d_in[7];
    const float* W2     = (const float*)d_in[8];
    const float* b2v    = (const float*)d_in[9];
    const float* gamma0 = (const float*)d_in[10];
    const float* beta0  = (const float*)d_in[11];
    const float* gamma1 = (const float*)d_in[12];
    const float* beta1  = (const float*)d_in[13];
    float* out = (float*)d_out;

    const size_t BN3  = (size_t)B * N * 3;
    const size_t H1FL = (size_t)B * N * 32;        // 12.8M fl = 51.2 MB
    const size_t UCFL = (size_t)4 * N * 32;        // 6.4M fl  = 25.6 MB
    const size_t XBFL = (size_t)B * N * 2;

    auto rnd = [](size_t nf) { return (nf + 63) & ~(size_t)63; };
    size_t off = 0;
    auto alloc = [&](size_t nfloats) -> float* {
        float* p = (float*)d_ws + off;
        off += rnd(nfloats);
        return p;
    };
    float* deg     = alloc(N);                     // becomes dis after dis_kernel
    int*   rowptr  = (int*)alloc(N + 1);
    int*   part    = (int*)alloc(N);
    int*   bsum    = (int*)alloc(256);
    int*   boff    = (int*)alloc(256);
    int*   cursor  = (int*)alloc(N);
    int*   csr_src = (int*)alloc(E);
    float* h1      = alloc(H1FL);

    const size_t avail_fl = ws_size / 4;
    const size_t need_full = off + 2 * H1FL + 4096;
    bool full = (avail_fl >= need_full);

    float *uA, *uB, *uC = nullptr;
    if (full) {
        uA = alloc(H1FL);
        uB = alloc(H1FL);
    } else {
        uA = alloc(UCFL);
        uB = alloc(UCFL);                          // contiguous: uB == uA + UCFL
        uC = alloc(UCFL);
    }
    uint2* xb1 = (uint2*)uA;
    uint2* xb2 = (uint2*)((float*)uA + XBFL);
    uint2* xb3 = (uint2*)((float*)uA + 2 * XBFL);
    float* y   = h1;
    float* v_a = h1 + rnd(4 * BN3);
    float* v_b = v_a + rnd(BN3);

    const int GE  = (E + 255) / 256;
    const int GN  = (N + 255) / 256;               // 196
    const int GB8 = GN * 8;
    const int GH4 = GN * 4;
    const int GW  = (N * 64) / 256;
    dim3 blk(256);

    // CSR build
    hipMemsetAsync(deg, 0, N * sizeof(float), stream);
    hipMemsetAsync(cursor, 0, N * sizeof(int), stream);
    deg_kernel<<<GE, blk, 0, stream>>>(coli, deg);
    scan1_kernel<<<GN, blk, 0, stream>>>(deg, part, bsum);
    scan2_kernel<<<1, blk, 0, stream>>>(bsum, boff, GN, rowptr);
    scan3_kernel<<<GN, blk, 0, stream>>>(part, boff, rowptr);
    fill_kernel<<<GE, blk, 0, stream>>>(rowi, coli, rowptr, cursor, csr_src);
    dis_kernel<<<GN, blk, 0, stream>>>(deg);       // deg -> dis in place
    const float* dis = deg;

    // layer 0
    xprop_kernel<false><<<GB8, blk, 0, stream>>>(x,   rowptr, csr_src, dis, xb1);
    xprop_kernel<true><<<GB8, blk, 0, stream>>>(xb1, rowptr, csr_src, dis, xb2);
    xprop_kernel<true><<<GB8, blk, 0, stream>>>(xb2, rowptr, csr_src, dis, xb3);
    build_h1_kernel<<<GW, blk, 0, stream>>>((const float4*)x, xb1, xb2, xb3, W0, gamma0, beta0, (uint4*)h1);

    const uint4* H1 = (const uint4*)h1;
    if (full) {
        hopM_kernel<0><<<GB8, blk, 0, stream>>>(nullptr, rowptr, csr_src, dis, H1, 0, 7, 3,
                                                W1 + 3 * 4096, nullptr, (uint4*)uA);
        hopM_kernel<1><<<GB8, blk, 0, stream>>>((const uint4*)uA, rowptr, csr_src, dis, H1, 0, 7, 3,
                                                W1 + 2 * 4096, nullptr, (uint4*)uB);
        hopM_kernel<1><<<GB8, blk, 0, stream>>>((const uint4*)uB, rowptr, csr_src, dis, H1, 0, 7, 3,
                                                W1 + 1 * 4096, nullptr, (uint4*)uA);
        hopM_kernel<2><<<GB8, blk, 0, stream>>>((const uint4*)uA, rowptr, csr_src, dis, H1, 0, 7, 3,
                                                W1, b1v, (uint4*)uB);
        bn_project_kernel<<<GW, blk, 0, stream>>>((const uint4*)uB, (const uint4*)(uB + 4 * (size_t)N * 32),
                                                  gamma1, beta1, W2, y);
    } else {
        hopM_kernel<0><<<GB8, blk, 0, stream>>>(nullptr, rowptr, csr_src, dis, H1, 0, 7, 3,
                                                W1 + 3 * 4096, nullptr, (uint4*)uA);
        // lo chunk: uA -> uC -> uA -> uC(z_lo)
        hopM_kernel<1><<<GH4, blk, 0, stream>>>((const uint4*)uA, rowptr, csr_src, dis, H1, 0, 3, 2,
                                                W1 + 2 * 4096, nullptr, (uint4*)uC);
        hopM_kernel<1><<<GH4, blk, 0, stream>>>((const uint4*)uC, rowptr, csr_src, dis, H1, 0, 3, 2,
                                                W1 + 1 * 4096, nullptr, (uint4*)uA);
        hopM_kernel<2><<<GH4, blk, 0, stream>>>((const uint4*)uA, rowptr, csr_src, dis, H1, 0, 3, 2,
                                                W1, b1v, (uint4*)uC);
        // hi chunk: uB -> uA -> uB -> uA(z_hi)
        hopM_kernel<1><<<GH4, blk, 0, stream>>>((const uint4*)uB, rowptr, csr_src, dis, H1, 4, 3, 2,
                                                W1 + 2 * 4096, nullptr, (uint4*)uA);
        hopM_kernel<1><<<GH4, blk, 0, stream>>>((const uint4*)uA, rowptr, csr_src, dis, H1, 4, 3, 2,
                                                W1 + 1 * 4096, nullptr, (uint4*)uB);
        hopM_kernel<2><<<GH4, blk, 0, stream>>>((const uint4*)uB, rowptr, csr_src, dis, H1, 4, 3, 2,
                                                W1, b1v, (uint4*)uA);
        bn_project_kernel<<<GW, blk, 0, stream>>>((const uint4*)uC, (const uint4*)uA,
                                                  gamma1, beta1, W2, y);
    }

    // layer 2 Horner at 3-dim
    qprop_kernel<<<GB8, blk, 0, stream>>>(y + 3 * BN3, rowptr, csr_src, dis, y + 2 * BN3, v_a);
    qprop_kernel<<<GB8, blk, 0, stream>>>(v_a, rowptr, csr_src, dis, y + 1 * BN3, v_b);
    qfinal_kernel<<<GB8, blk, 0, stream>>>(v_b, rowptr, csr_src, dis, y, b2v, vmin, vmax, out);
}

// Round 9
// 926.333 us; speedup vs baseline: 2.4763x; 1.0021x over previous
//
#include <hip/hip_runtime.h>
#include <math.h>

constexpr int B = 8;
constexpr int N = 50000;
constexpr int E = 400000;
constexpr int NH = 25000;       // source-bucket split point (3.2 MB per bucket slice)
constexpr float BN_EPS = 1e-5f;
constexpr float NEG = 0.01f;

// ------------------------- bf16 helpers -------------------------

__device__ __forceinline__ unsigned clamp_src(int s) {
    unsigned u = (unsigned)s;
    return (u < (unsigned)N) ? u : 0u;
}

__device__ __forceinline__ unsigned pack_bf16(float a, float b) {
    unsigned ua = __float_as_uint(a);
    unsigned ub = __float_as_uint(b);
    ua = (ua + 0x7FFFu + ((ua >> 16) & 1u)) >> 16;
    ub = (ub + 0x7FFFu + ((ub >> 16) & 1u)) >> 16;
    return (ub << 16) | (ua & 0xFFFFu);
}
__device__ __forceinline__ float unpack_lo(unsigned u) { return __uint_as_float(u << 16); }
__device__ __forceinline__ float unpack_hi(unsigned u) { return __uint_as_float(u & 0xFFFF0000u); }

__device__ __forceinline__ void store_row64_bf(uint4* p, const float acc[64]) {
#pragma unroll
    for (int q = 0; q < 8; ++q) {
        uint4 v;
        v.x = pack_bf16(acc[q * 8 + 0], acc[q * 8 + 1]);
        v.y = pack_bf16(acc[q * 8 + 2], acc[q * 8 + 3]);
        v.z = pack_bf16(acc[q * 8 + 4], acc[q * 8 + 5]);
        v.w = pack_bf16(acc[q * 8 + 6], acc[q * 8 + 7]);
        p[q] = v;
    }
}

// ------------------------- CSR construction (source-bucketed) -------------------------

__global__ __launch_bounds__(256) void deg2_kernel(const int* __restrict__ row, const int* __restrict__ col,
                                                   float* __restrict__ deg, int* __restrict__ deg_lo) {
    int e = blockIdx.x * blockDim.x + threadIdx.x;
    if (e >= E) return;
    unsigned r = clamp_src(row[e]), c = clamp_src(col[e]);
    atomicAdd(&deg[c], 1.0f);
    if (r < (unsigned)NH) atomicAdd(&deg_lo[c], 1);
}

__global__ __launch_bounds__(256) void scan1_kernel(const float* __restrict__ deg,
                                                    int* __restrict__ part, int* __restrict__ bsum) {
    __shared__ int sm[4];
    int i = blockIdx.x * blockDim.x + threadIdx.x;
    int v = (i < N) ? (int)deg[i] : 0;
    int lane = threadIdx.x & 63, wv = threadIdx.x >> 6;
    int x = v;
#pragma unroll
    for (int off = 1; off < 64; off <<= 1) {
        int t = __shfl_up(x, off);
        if (lane >= off) x += t;
    }
    if (lane == 63) sm[wv] = x;
    __syncthreads();
    int add = 0;
#pragma unroll
    for (int w = 0; w < 4; ++w) if (w < wv) add += sm[w];
    if (i < N) part[i] = x - v + add;
    if (threadIdx.x == blockDim.x - 1) bsum[blockIdx.x] = x + add;
}

__global__ __launch_bounds__(256) void scan2_kernel(const int* __restrict__ bsum, int* __restrict__ boff,
                                                    int nb, int* __restrict__ rowptr) {
    __shared__ int sm[4];
    int i = threadIdx.x;
    int v = (i < nb) ? bsum[i] : 0;
    int lane = i & 63, wv = i >> 6;
    int x = v;
#pragma unroll
    for (int off = 1; off < 64; off <<= 1) {
        int t = __shfl_up(x, off);
        if (lane >= off) x += t;
    }
    if (lane == 63) sm[wv] = x;
    __syncthreads();
    int add = 0;
#pragma unroll
    for (int w = 0; w < 4; ++w) if (w < wv) add += sm[w];
    if (i < nb) boff[i] = x - v + add;
    if (i == 0) rowptr[N] = E;
}

__global__ __launch_bounds__(256) void scan3_kernel(const int* __restrict__ part, const int* __restrict__ boff,
                                                    int* __restrict__ rowptr) {
    int i = blockIdx.x * blockDim.x + threadIdx.x;
    if (i < N) rowptr[i] = part[i] + boff[blockIdx.x];
}

// bucketed fill: lo-source edges at [rowptr, rowptr+deg_lo), hi at [rowptr+deg_lo, next)
__global__ __launch_bounds__(256) void fill_kernel(const int* __restrict__ row, const int* __restrict__ col,
                                                   const int* __restrict__ rowptr, const int* __restrict__ deg_lo,
                                                   int* __restrict__ cur_lo, int* __restrict__ cur_hi,
                                                   int* __restrict__ csr_src) {
    int e = blockIdx.x * blockDim.x + threadIdx.x;
    if (e >= E) return;
    unsigned r = clamp_src(row[e]), c = clamp_src(col[e]);
    unsigned p;
    if (r < (unsigned)NH)
        p = (unsigned)(rowptr[c] + atomicAdd(&cur_lo[c], 1));
    else
        p = (unsigned)(rowptr[c] + deg_lo[c] + atomicAdd(&cur_hi[c], 1));
    if (p >= (unsigned)E) p = E - 1;   // defensive
    csr_src[p] = (int)r;
}

// deg -> dis (in place): dis = deg>0 ? deg^-1/2 : 0
__global__ __launch_bounds__(256) void dis_kernel(float* __restrict__ deg) {
    int i = blockIdx.x * blockDim.x + threadIdx.x;
    if (i < N) {
        float d = deg[i];
        deg[i] = (d > 0.f) ? rsqrtf(d) : 0.f;
    }
}

// ------------------------- 4-dim propagation (layer 0), batch-pinned, bf16 out ---------

template<bool INBF>
__global__ __launch_bounds__(256) void xprop_kernel(const void* __restrict__ xin, const int* __restrict__ rowptr,
                                                    const int* __restrict__ csr_src, const float* __restrict__ dis,
                                                    uint2* __restrict__ xout) {
    int b = blockIdx.x & 7;
    int n = (blockIdx.x >> 3) * blockDim.x + threadIdx.x;
    if (n >= N) return;
    float a0 = 0.f, a1 = 0.f, a2 = 0.f, a3 = 0.f;
    int beg = rowptr[n], end = rowptr[n + 1];
    if (beg < 0) beg = 0;
    if (end > E) end = E;
    for (int i = beg; i < end; ++i) {
        unsigned s = clamp_src(csr_src[i]);
        float w = dis[s];
        if constexpr (!INBF) {
            float4 v = *((const float4*)xin + (size_t)b * N + s);
            a0 = fmaf(w, v.x, a0); a1 = fmaf(w, v.y, a1);
            a2 = fmaf(w, v.z, a2); a3 = fmaf(w, v.w, a3);
        } else {
            uint2 v = *((const uint2*)xin + (size_t)b * N + s);
            a0 = fmaf(w, unpack_lo(v.x), a0); a1 = fmaf(w, unpack_hi(v.x), a1);
            a2 = fmaf(w, unpack_lo(v.y), a2); a3 = fmaf(w, unpack_hi(v.y), a3);
        }
    }
    float dn = dis[n];
    uint2 o;
    o.x = pack_bf16(a0 * dn, a1 * dn);
    o.y = pack_bf16(a2 * dn, a3 * dn);
    xout[(size_t)b * N + n] = o;
}

// ------------------------- 16-dim concat row loader -------------------------

__device__ __forceinline__ void load_xv(const float4* __restrict__ x0, const uint2* __restrict__ x1,
                                        const uint2* __restrict__ x2, const uint2* __restrict__ x3,
                                        size_t ro, float xv[16]) {
    float4 v = x0[ro];
    xv[0] = v.x; xv[1] = v.y; xv[2] = v.z; xv[3] = v.w;
    uint2 u1 = x1[ro], u2 = x2[ro], u3 = x3[ro];
    xv[4] = unpack_lo(u1.x); xv[5] = unpack_hi(u1.x); xv[6] = unpack_lo(u1.y); xv[7] = unpack_hi(u1.y);
    xv[8] = unpack_lo(u2.x); xv[9] = unpack_hi(u2.x); xv[10] = unpack_lo(u2.y); xv[11] = unpack_hi(u2.y);
    xv[12] = unpack_lo(u3.x); xv[13] = unpack_hi(u3.x); xv[14] = unpack_lo(u3.y); xv[15] = unpack_hi(u3.y);
}

// ------------------------- build h1 = leaky(BN0([x|x1|x2|x3] @ W0)), bf16 full batch ----

__global__ __launch_bounds__(256) void build_h1_kernel(const float4* __restrict__ x0, const uint2* __restrict__ x1,
                                                       const uint2* __restrict__ x2, const uint2* __restrict__ x3,
                                                       const float* __restrict__ W0,
                                                       const float* __restrict__ gamma, const float* __restrict__ beta,
                                                       uint4* __restrict__ h1) {
    int gid = blockIdx.x * blockDim.x + threadIdx.x;
    int node = gid >> 6;
    int lane = gid & 63;
    int fg = lane >> 3, b = lane & 7;
    if (node >= N) return;
    size_t ro = (size_t)b * N + node;
    float xv[16];
    load_xv(x0, x1, x2, x3, ro, xv);
    float z[8];
#pragma unroll
    for (int j = 0; j < 8; ++j) z[j] = 0.f;
#pragma unroll
    for (int kf = 0; kf < 16; ++kf) {
        const float* wr = W0 + kf * 64 + fg * 8;
        float4 wa = *(const float4*)wr;
        float4 wb = *(const float4*)(wr + 4);
        float xs = xv[kf];
        z[0] = fmaf(xs, wa.x, z[0]); z[1] = fmaf(xs, wa.y, z[1]);
        z[2] = fmaf(xs, wa.z, z[2]); z[3] = fmaf(xs, wa.w, z[3]);
        z[4] = fmaf(xs, wb.x, z[4]); z[5] = fmaf(xs, wb.y, z[5]);
        z[6] = fmaf(xs, wb.z, z[6]); z[7] = fmaf(xs, wb.w, z[7]);
    }
    const float* gp = gamma + (size_t)node * 64 + fg * 8;
    const float* bp = beta + (size_t)node * 64 + fg * 8;
    float h[8];
#pragma unroll
    for (int j = 0; j < 8; ++j) {
        float v = z[j];
        float s = v, s2 = v * v;
        s += __shfl_xor(s, 1);  s += __shfl_xor(s, 2);  s += __shfl_xor(s, 4);
        s2 += __shfl_xor(s2, 1); s2 += __shfl_xor(s2, 2); s2 += __shfl_xor(s2, 4);
        float mean = s * 0.125f;
        float var = fmaf(-mean, mean, s2 * 0.125f);
        float rs = rsqrtf(var + BN_EPS);
        float o = fmaf(gp[j] * rs, v - mean, bp[j]);
        h[j] = (o >= 0.f) ? o : NEG * o;
    }
    uint4 o;
    o.x = pack_bf16(h[0], h[1]);
    o.y = pack_bf16(h[2], h[3]);
    o.z = pack_bf16(h[4], h[5]);
    o.w = pack_bf16(h[6], h[7]);
    h1[ro * 8 + fg] = o;
}

// ------------------------- bf16 gather (pair-pipelined) + dense 64x64 -------------------

__device__ __forceinline__ void fma_row(float acc[64], float w, const uint4 r[8]) {
#pragma unroll
    for (int q = 0; q < 8; ++q) {
        uint4 v = r[q];
        acc[q * 8 + 0] = fmaf(w, unpack_lo(v.x), acc[q * 8 + 0]);
        acc[q * 8 + 1] = fmaf(w, unpack_hi(v.x), acc[q * 8 + 1]);
        acc[q * 8 + 2] = fmaf(w, unpack_lo(v.y), acc[q * 8 + 2]);
        acc[q * 8 + 3] = fmaf(w, unpack_hi(v.y), acc[q * 8 + 3]);
        acc[q * 8 + 4] = fmaf(w, unpack_lo(v.z), acc[q * 8 + 4]);
        acc[q * 8 + 5] = fmaf(w, unpack_hi(v.z), acc[q * 8 + 5]);
        acc[q * 8 + 6] = fmaf(w, unpack_lo(v.w), acc[q * 8 + 6]);
        acc[q * 8 + 7] = fmaf(w, unpack_hi(v.w), acc[q * 8 + 7]);
    }
}

__device__ __forceinline__ void gather64_bf(const uint4* __restrict__ ub8, int beg, int end,
                                            const int* __restrict__ csr_src, const float* __restrict__ dis,
                                            float acc[64]) {
    if (beg < 0) beg = 0;
    if (end > E) end = E;
    int i = beg;
    for (; i + 1 < end; i += 2) {
        unsigned s0 = clamp_src(csr_src[i]);
        unsigned s1 = clamp_src(csr_src[i + 1]);
        float w0 = dis[s0], w1 = dis[s1];
        const uint4* p0 = ub8 + (size_t)s0 * 8;
        const uint4* p1 = ub8 + (size_t)s1 * 8;
        uint4 r0[8], r1[8];
#pragma unroll
        for (int q = 0; q < 8; ++q) r0[q] = p0[q];
#pragma unroll
        for (int q = 0; q < 8; ++q) r1[q] = p1[q];
        fma_row(acc, w0, r0);
        fma_row(acc, w1, r1);
    }
    if (i < end) {
        unsigned s0 = clamp_src(csr_src[i]);
        float w0 = dis[s0];
        const uint4* p0 = ub8 + (size_t)s0 * 8;
        uint4 r0[8];
#pragma unroll
        for (int q = 0; q < 8; ++q) r0[q] = p0[q];
        fma_row(acc, w0, r0);
    }
}

__device__ __forceinline__ void dense64_bf(const uint4* __restrict__ hp8, const float* __restrict__ W, float acc[64]) {
#pragma unroll 1
    for (int kk = 0; kk < 4; ++kk) {
        float hreg[16];
        uint4 va = hp8[kk * 2], vb = hp8[kk * 2 + 1];
        hreg[0] = unpack_lo(va.x); hreg[1] = unpack_hi(va.x);
        hreg[2] = unpack_lo(va.y); hreg[3] = unpack_hi(va.y);
        hreg[4] = unpack_lo(va.z); hreg[5] = unpack_hi(va.z);
        hreg[6] = unpack_lo(va.w); hreg[7] = unpack_hi(va.w);
        hreg[8] = unpack_lo(vb.x); hreg[9] = unpack_hi(vb.x);
        hreg[10] = unpack_lo(vb.y); hreg[11] = unpack_hi(vb.y);
        hreg[12] = unpack_lo(vb.z); hreg[13] = unpack_hi(vb.z);
        hreg[14] = unpack_lo(vb.w); hreg[15] = unpack_hi(vb.w);
        const float* Wp = W + kk * 16 * 64;
#pragma unroll
        for (int k = 0; k < 16; ++k) {
            float hv = hreg[k];
#pragma unroll
            for (int c = 0; c < 64; ++c)
                acc[c] = fmaf(hv, Wp[k * 64 + c], acc[c]);
        }
    }
}

// ------------------------- Horner hop (full 64-feature row / thread) -------------------
// MODE 0: u_out = h1@Wk. MODE 1: u_out = dis_n*(A' u_in) + h1@Wk. MODE 2: + bias.

template<int MODE>
__global__ __launch_bounds__(256) void hopM_kernel(const uint4* __restrict__ u_in, const int* __restrict__ rowptr,
                                                   const int* __restrict__ csr_src, const float* __restrict__ dis,
                                                   const uint4* __restrict__ h1, int b0, int bmask, int bshift,
                                                   const float* __restrict__ Wk, const float* __restrict__ bias,
                                                   uint4* __restrict__ u_out) {
    int bl = blockIdx.x & bmask;
    int n = (blockIdx.x >> bshift) * blockDim.x + threadIdx.x;
    if (n >= N) return;
    float acc[64];
#pragma unroll
    for (int f = 0; f < 64; ++f) acc[f] = 0.f;
    if constexpr (MODE > 0) {
        gather64_bf(u_in + (size_t)bl * N * 8, rowptr[n], rowptr[n + 1], csr_src, dis, acc);
        float dn = dis[n];
#pragma unroll
        for (int f = 0; f < 64; ++f) acc[f] *= dn;
    }
    if constexpr (MODE == 2) {
#pragma unroll
        for (int f = 0; f < 64; ++f) acc[f] += bias[f];
    }
    dense64_bf(h1 + ((size_t)(b0 + bl) * N + n) * 8, Wk, acc);
    store_row64_bf(u_out + ((size_t)bl * N + n) * 8, acc);
}

// ------------------------- BN1 + leaky + W2 projection -------------------------

__global__ __launch_bounds__(256) void bn_project_kernel(const uint4* __restrict__ zlo, const uint4* __restrict__ zhi,
                                                         const float* __restrict__ gamma, const float* __restrict__ beta,
                                                         const float* __restrict__ W2, float* __restrict__ y) {
    int gid = blockIdx.x * blockDim.x + threadIdx.x;
    int node = gid >> 6;
    int lane = gid & 63;
    int fg = lane >> 3, b = lane & 7;
    if (node >= N) return;
    const uint4* zp = (b < 4) ? (zlo + ((size_t)b * N + node) * 8)
                              : (zhi + ((size_t)(b - 4) * N + node) * 8);
    uint4 v = zp[fg];
    float h[8] = {unpack_lo(v.x), unpack_hi(v.x), unpack_lo(v.y), unpack_hi(v.y),
                  unpack_lo(v.z), unpack_hi(v.z), unpack_lo(v.w), unpack_hi(v.w)};
    const float* gp = gamma + (size_t)node * 64 + fg * 8;
    const float* bp = beta + (size_t)node * 64 + fg * 8;
#pragma unroll
    for (int j = 0; j < 8; ++j) {
        float val = h[j];
        float s = val, s2 = val * val;
        s += __shfl_xor(s, 1);  s += __shfl_xor(s, 2);  s += __shfl_xor(s, 4);
        s2 += __shfl_xor(s2, 1); s2 += __shfl_xor(s2, 2); s2 += __shfl_xor(s2, 4);
        float mean = s * 0.125f;
        float var = fmaf(-mean, mean, s2 * 0.125f);
        float rs = rsqrtf(var + BN_EPS);
        float o = fmaf(gp[j] * rs, val - mean, bp[j]);
        h[j] = (o >= 0.f) ? o : NEG * o;
    }
    float p[12];
#pragma unroll
    for (int k = 0; k < 4; ++k) {
#pragma unroll
        for (int c = 0; c < 3; ++c) {
            float s = 0.f;
#pragma unroll
            for (int j = 0; j < 8; ++j)
                s = fmaf(h[j], W2[k * 192 + (fg * 8 + j) * 3 + c], s);
            p[k * 3 + c] = s;
        }
    }
#pragma unroll
    for (int t = 8; t < 64; t <<= 1) {
#pragma unroll
        for (int i = 0; i < 12; ++i)
            p[i] += __shfl_xor(p[i], t);
    }
    if (fg == 0) {
        size_t bn3 = ((size_t)b * N + node) * 3;
#pragma unroll
        for (int k = 0; k < 4; ++k)
#pragma unroll
            for (int c = 0; c < 3; ++c)
                y[(size_t)k * B * N * 3 + bn3 + c] = p[k * 3 + c];
    }
}

// ------------------------- 3-dim propagation (layer 2 Horner) -------------------------

__global__ __launch_bounds__(256) void qprop_kernel(const float* __restrict__ vin, const int* __restrict__ rowptr,
                                                    const int* __restrict__ csr_src, const float* __restrict__ dis,
                                                    const float* __restrict__ add, float* __restrict__ vout) {
    int b = blockIdx.x & 7;
    int n = (blockIdx.x >> 3) * blockDim.x + threadIdx.x;
    if (n >= N) return;
    float a0 = 0.f, a1 = 0.f, a2 = 0.f;
    int beg = rowptr[n], end = rowptr[n + 1];
    if (beg < 0) beg = 0;
    if (end > E) end = E;
    const float* base = vin + (size_t)b * N * 3;
    for (int i = beg; i < end; ++i) {
        unsigned s = clamp_src(csr_src[i]);
        float w = dis[s];
        const float* p = base + (size_t)s * 3;
        a0 = fmaf(w, p[0], a0);
        a1 = fmaf(w, p[1], a1);
        a2 = fmaf(w, p[2], a2);
    }
    float dn = dis[n];
    const float* ap = add + ((size_t)b * N + n) * 3;
    float* op = vout + ((size_t)b * N + n) * 3;
    op[0] = fmaf(a0, dn, ap[0]);
    op[1] = fmaf(a1, dn, ap[1]);
    op[2] = fmaf(a2, dn, ap[2]);
}

__global__ __launch_bounds__(256) void qfinal_kernel(const float* __restrict__ vin, const int* __restrict__ rowptr,
                                                     const int* __restrict__ csr_src, const float* __restrict__ dis,
                                                     const float* __restrict__ y0, const float* __restrict__ b2,
                                                     const float* __restrict__ vmin, const float* __restrict__ vmax,
                                                     float* __restrict__ out) {
    int b = blockIdx.x & 7;
    int n = (blockIdx.x >> 3) * blockDim.x + threadIdx.x;
    if (n >= N) return;
    float a0 = 0.f, a1 = 0.f, a2 = 0.f;
    int beg = rowptr[n], end = rowptr[n + 1];
    if (beg < 0) beg = 0;
    if (end > E) end = E;
    const float* base = vin + (size_t)b * N * 3;
    for (int i = beg; i < end; ++i) {
        unsigned s = clamp_src(csr_src[i]);
        float w = dis[s];
        const float* p = base + (size_t)s * 3;
        a0 = fmaf(w, p[0], a0);
        a1 = fmaf(w, p[1], a1);
        a2 = fmaf(w, p[2], a2);
    }
    float dn = dis[n];
    size_t bn3 = ((size_t)b * N + n) * 3;
    const float* yp = y0 + bn3;
    float g0 = fmaf(a0, dn, yp[0]) + b2[0];
    float g1 = fmaf(a1, dn, yp[1]) + b2[1];
    float g2 = fmaf(a2, dn, yp[2]) + b2[2];
    float mn0 = vmin[n * 3 + 0], mx0 = vmax[n * 3 + 0];
    float mn1 = vmin[n * 3 + 1], mx1 = vmax[n * 3 + 1];
    float mn2 = vmin[n * 3 + 2], mx2 = vmax[n * 3 + 2];
    float* op = out + bn3;
    op[0] = mn0 + (mx0 - mn0) / (1.f + expf(g0));
    op[1] = mn1 + (mx1 - mn1) / (1.f + expf(g1));
    op[2] = mn2 + (mx2 - mn2) / (1.f + expf(g2));
}

// ------------------------- host launcher -------------------------

extern "C" void kernel_launch(void* const* d_in, const int* in_sizes, int n_in,
                              void* d_out, int out_size, void* d_ws, size_t ws_size,
                              hipStream_t stream) {
    const float* x      = (const float*)d_in[0];
    const int*   ei     = (const int*)d_in[1];
    const int*   rowi   = ei;
    const int*   coli   = ei + E;
    const float* vmin   = (const float*)d_in[2];
    const float* vmax   = (const float*)d_in[3];
    const float* W0     = (const float*)d_in[4];
    const float* W1     = (const float*)d_in[6];
    const float* b1v    = (const float*)d_in[7];
    const float* W2     = (const float*)d_in[8];
    const float* b2v    = (const float*)d_in[9];
    const float* gamma0 = (const float*)d_in[10];
    const float* beta0  = (const float*)d_in[11];
    const float* gamma1 = (const float*)d_in[12];
    const float* beta1  = (const float*)d_in[13];
    float* out = (float*)d_out;

    const size_t BN3  = (size_t)B * N * 3;
    const size_t H1FL = (size_t)B * N * 32;        // 12.8M fl = 51.2 MB
    const size_t UCFL = (size_t)4 * N * 32;        // 6.4M fl  = 25.6 MB
    const size_t XBFL = (size_t)B * N * 2;

    auto rnd = [](size_t nf) { return (nf + 63) & ~(size_t)63; };
    size_t off = 0;
    auto alloc = [&](size_t nfloats) -> float* {
        float* p = (float*)d_ws + off;
        off += rnd(nfloats);
        return p;
    };
    float* deg     = alloc(N);                     // becomes dis after dis_kernel
    int*   deg_lo  = (int*)alloc(N);
    int*   rowptr  = (int*)alloc(N + 1);
    int*   part    = (int*)alloc(N);
    int*   bsum    = (int*)alloc(256);
    int*   boff    = (int*)alloc(256);
    int*   cur_lo  = (int*)alloc(N);
    int*   cur_hi  = (int*)alloc(N);
    int*   csr_src = (int*)alloc(E);
    float* h1      = alloc(H1FL);

    const size_t avail_fl = ws_size / 4;
    const size_t need_full = off + 2 * H1FL + 4096;
    bool full = (avail_fl >= need_full);

    float *uA, *uB, *uC = nullptr;
    if (full) {
        uA = alloc(H1FL);
        uB = alloc(H1FL);
    } else {
        uA = alloc(UCFL);
        uB = alloc(UCFL);                          // contiguous: uB == uA + UCFL
        uC = alloc(UCFL);
    }
    uint2* xb1 = (uint2*)uA;
    uint2* xb2 = (uint2*)((float*)uA + XBFL);
    uint2* xb3 = (uint2*)((float*)uA + 2 * XBFL);
    float* y   = h1;
    float* v_a = h1 + rnd(4 * BN3);
    float* v_b = v_a + rnd(BN3);

    const int GE  = (E + 255) / 256;
    const int GN  = (N + 255) / 256;               // 196
    const int GB8 = GN * 8;
    const int GH4 = GN * 4;
    const int GW  = (N * 64) / 256;
    dim3 blk(256);

    // CSR build (source-bucketed)
    hipMemsetAsync(deg, 0, N * sizeof(float), stream);
    hipMemsetAsync(deg_lo, 0, N * sizeof(int), stream);
    hipMemsetAsync(cur_lo, 0, N * sizeof(int), stream);
    hipMemsetAsync(cur_hi, 0, N * sizeof(int), stream);
    deg2_kernel<<<GE, blk, 0, stream>>>(rowi, coli, deg, deg_lo);
    scan1_kernel<<<GN, blk, 0, stream>>>(deg, part, bsum);
    scan2_kernel<<<1, blk, 0, stream>>>(bsum, boff, GN, rowptr);
    scan3_kernel<<<GN, blk, 0, stream>>>(part, boff, rowptr);
    fill_kernel<<<GE, blk, 0, stream>>>(rowi, coli, rowptr, deg_lo, cur_lo, cur_hi, csr_src);
    dis_kernel<<<GN, blk, 0, stream>>>(deg);       // deg -> dis in place
    const float* dis = deg;

    // layer 0
    xprop_kernel<false><<<GB8, blk, 0, stream>>>(x,   rowptr, csr_src, dis, xb1);
    xprop_kernel<true><<<GB8, blk, 0, stream>>>(xb1, rowptr, csr_src, dis, xb2);
    xprop_kernel<true><<<GB8, blk, 0, stream>>>(xb2, rowptr, csr_src, dis, xb3);
    build_h1_kernel<<<GW, blk, 0, stream>>>((const float4*)x, xb1, xb2, xb3, W0, gamma0, beta0, (uint4*)h1);

    const uint4* H1 = (const uint4*)h1;
    if (full) {
        hopM_kernel<0><<<GB8, blk, 0, stream>>>(nullptr, rowptr, csr_src, dis, H1, 0, 7, 3,
                                                W1 + 3 * 4096, nullptr, (uint4*)uA);
        hopM_kernel<1><<<GB8, blk, 0, stream>>>((const uint4*)uA, rowptr, csr_src, dis, H1, 0, 7, 3,
                                                W1 + 2 * 4096, nullptr, (uint4*)uB);
        hopM_kernel<1><<<GB8, blk, 0, stream>>>((const uint4*)uB, rowptr, csr_src, dis, H1, 0, 7, 3,
                                                W1 + 1 * 4096, nullptr, (uint4*)uA);
        hopM_kernel<2><<<GB8, blk, 0, stream>>>((const uint4*)uA, rowptr, csr_src, dis, H1, 0, 7, 3,
                                                W1, b1v, (uint4*)uB);
        bn_project_kernel<<<GW, blk, 0, stream>>>((const uint4*)uB, (const uint4*)(uB + 4 * (size_t)N * 32),
                                                  gamma1, beta1, W2, y);
    } else {
        hopM_kernel<0><<<GB8, blk, 0, stream>>>(nullptr, rowptr, csr_src, dis, H1, 0, 7, 3,
                                                W1 + 3 * 4096, nullptr, (uint4*)uA);
        hopM_kernel<1><<<GH4, blk, 0, stream>>>((const uint4*)uA, rowptr, csr_src, dis, H1, 0, 3, 2,
                                                W1 + 2 * 4096, nullptr, (uint4*)uC);
        hopM_kernel<1><<<GH4, blk, 0, stream>>>((const uint4*)uC, rowptr, csr_src, dis, H1, 0, 3, 2,
                                                W1 + 1 * 4096, nullptr, (uint4*)uA);
        hopM_kernel<2><<<GH4, blk, 0, stream>>>((const uint4*)uA, rowptr, csr_src, dis, H1, 0, 3, 2,
                                                W1, b1v, (uint4*)uC);
        hopM_kernel<1><<<GH4, blk, 0, stream>>>((const uint4*)uB, rowptr, csr_src, dis, H1, 4, 3, 2,
                                                W1 + 2 * 4096, nullptr, (uint4*)uA);
        hopM_kernel<1><<<GH4, blk, 0, stream>>>((const uint4*)uA, rowptr, csr_src, dis, H1, 4, 3, 2,
                                                W1 + 1 * 4096, nullptr, (uint4*)uB);
        hopM_kernel<2><<<GH4, blk, 0, stream>>>((const uint4*)uB, rowptr, csr_src, dis, H1, 4, 3, 2,
                                                W1, b1v, (uint4*)uA);
        bn_project_kernel<<<GW, blk, 0, stream>>>((const uint4*)uC, (const uint4*)uA,
                                                  gamma1, beta1, W2, y);
    }

    // layer 2 Horner at 3-dim
    qprop_kernel<<<GB8, blk, 0, stream>>>(y + 3 * BN3, rowptr, csr_src, dis, y + 2 * BN3, v_a);
    qprop_kernel<<<GB8, blk, 0, stream>>>(v_a, rowptr, csr_src, dis, y + 1 * BN3, v_b);
    qfinal_kernel<<<GB8, blk, 0, stream>>>(v_b, rowptr, csr_src, dis, y, b2v, vmin, vmax, out);
}